// Round 1
// baseline (837.517 us; speedup 1.0000x reference)
//
#include <hip/hip_runtime.h>

// SAGEConv: h[50000,64] f32, src/dst[800000] int32, W[128,64] f32, b[64] f32
// out[50000,64] f32 = concat(h, mean_agg(h[src] -> dst)) @ W + b

#define IN_FEAT 64
#define N_NODES_MAX 50000

// ---------------- scatter: gather h[src], atomic-add into summed[dst] --------
__global__ __launch_bounds__(256) void sage_scatter(
    const float* __restrict__ h,
    const int* __restrict__ src,
    const int* __restrict__ dst,
    float* __restrict__ summed,
    float* __restrict__ deg,
    int n_edges)
{
    int tid = blockIdx.x * blockDim.x + threadIdx.x;
    int e = tid >> 4;            // 16 threads per edge
    if (e >= n_edges) return;
    int f = (tid & 15) << 2;     // 4 floats per thread

    int s = src[e];
    int d = dst[e];

    const float4 v = *(const float4*)(h + (size_t)s * IN_FEAT + f);
    float* o = summed + (size_t)d * IN_FEAT + f;
    atomicAdd(o + 0, v.x);
    atomicAdd(o + 1, v.y);
    atomicAdd(o + 2, v.z);
    atomicAdd(o + 3, v.w);
    if ((tid & 15) == 0) atomicAdd(deg + d, 1.0f);
}

// ---------------- node transform: out = [h, summed/deg] @ W + b --------------
__global__ __launch_bounds__(256) void sage_node(
    const float* __restrict__ h,
    const float* __restrict__ summed,
    const float* __restrict__ deg,
    const float* __restrict__ W,     // [128,64] row-major
    const float* __restrict__ b,
    float* __restrict__ out,
    int n_nodes)
{
    __shared__ float Wsh[128][64];   // 32 KB
    __shared__ float bsh[64];
    __shared__ float hsh[4][64];
    __shared__ float hnsh[4][64];

    int t = threadIdx.x;

    // Cooperatively stage W in LDS via float4 (2048 float4s, 8 per thread)
    {
        float4* wdst = (float4*)&Wsh[0][0];
        const float4* wsrc = (const float4*)W;
        #pragma unroll
        for (int i = 0; i < 8; ++i)
            wdst[t + i * 256] = wsrc[t + i * 256];
    }
    if (t < 64) bsh[t] = b[t];

    int ln = t >> 6;                 // local node 0..3
    int j  = t & 63;                 // output column
    int n  = blockIdx.x * 4 + ln;

    if (n < n_nodes) {
        hsh[ln][j] = h[(size_t)n * IN_FEAT + j];
        float dg = deg[n];
        float inv = 1.0f / fmaxf(dg, 1.0f);
        hnsh[ln][j] = summed[(size_t)n * IN_FEAT + j] * inv;
    }
    __syncthreads();
    if (n >= n_nodes) return;

    float acc = bsh[j];
    #pragma unroll
    for (int k = 0; k < 64; ++k) {
        acc = fmaf(hsh[ln][k],  Wsh[k][j],      acc);
        acc = fmaf(hnsh[ln][k], Wsh[64 + k][j], acc);
    }
    out[(size_t)n * IN_FEAT + j] = acc;
}

extern "C" void kernel_launch(void* const* d_in, const int* in_sizes, int n_in,
                              void* d_out, int out_size, void* d_ws, size_t ws_size,
                              hipStream_t stream) {
    const float* h   = (const float*)d_in[0];
    const int*   src = (const int*)d_in[1];
    const int*   dst = (const int*)d_in[2];
    const float* W   = (const float*)d_in[3];
    const float* b   = (const float*)d_in[4];
    float* out = (float*)d_out;

    const int n_nodes = in_sizes[0] / IN_FEAT;
    const int n_edges = in_sizes[1];

    float* summed = (float*)d_ws;                       // [n_nodes * 64]
    float* deg    = summed + (size_t)n_nodes * IN_FEAT; // [n_nodes]

    // zero accumulators (ws is re-poisoned to 0xAA before every timed call)
    size_t zero_bytes = (size_t)n_nodes * IN_FEAT * sizeof(float)
                      + (size_t)n_nodes * sizeof(float);
    hipMemsetAsync(d_ws, 0, zero_bytes, stream);

    // scatter: 16 threads/edge
    {
        long long total = (long long)n_edges * 16;
        int grid = (int)((total + 255) / 256);
        sage_scatter<<<grid, 256, 0, stream>>>(h, src, dst, summed, deg, n_edges);
    }

    // node transform: 4 nodes/block
    {
        int grid = (n_nodes + 3) / 4;
        sage_node<<<grid, 256, 0, stream>>>(h, summed, deg, W, b, out, n_nodes);
    }
}

// Round 2
// 315.782 us; speedup vs baseline: 2.6522x; 2.6522x over previous
//
#include <hip/hip_runtime.h>

// SAGEConv: h[50000,64] f32, src/dst[800000] int32, W[128,64] f32, b[64] f32
// out = concat(h, mean_{in-edges}(h[src])) @ W + b
//
// Strategy (R2): device-built CSR (by dst) + gather-side reduction.
// Kills the 51.2M device-scope float atomics (R1: 825 MB WRITE_SIZE, 718 us).

#define IN_FEAT 64

// ---- k1: degree histogram --------------------------------------------------
__global__ __launch_bounds__(256) void sage_hist(
    const int* __restrict__ dst, int* __restrict__ cnt, int n_edges)
{
    int e = blockIdx.x * blockDim.x + threadIdx.x;
    if (e < n_edges) atomicAdd(&cnt[dst[e]], 1);
}

// ---- k2: exclusive scan (single block, sequential chunks) ------------------
__global__ __launch_bounds__(1024) void sage_scan(
    const int* __restrict__ cnt, int* __restrict__ row_start,
    int* __restrict__ cursor, int n_nodes)
{
    __shared__ int sh[1024];
    int running = 0;
    for (int base = 0; base < n_nodes; base += 1024) {
        int i = base + (int)threadIdx.x;
        int v = (i < n_nodes) ? cnt[i] : 0;
        sh[threadIdx.x] = v;
        __syncthreads();
        // Hillis-Steele inclusive scan
        for (int off = 1; off < 1024; off <<= 1) {
            int t = (threadIdx.x >= (unsigned)off) ? sh[threadIdx.x - off] : 0;
            __syncthreads();
            sh[threadIdx.x] += t;
            __syncthreads();
        }
        int incl = sh[threadIdx.x];
        int excl = incl - v;
        if (i < n_nodes) {
            row_start[i] = running + excl;
            cursor[i]    = running + excl;
        }
        int total = sh[1023];
        __syncthreads();           // before next chunk overwrites sh
        running += total;
    }
    if (threadIdx.x == 0) row_start[n_nodes] = running;
}

// ---- k3: bucket edges by dst ----------------------------------------------
__global__ __launch_bounds__(256) void sage_fill(
    const int* __restrict__ src, const int* __restrict__ dst,
    int* __restrict__ cursor, int* __restrict__ csr_src, int n_edges)
{
    int e = blockIdx.x * blockDim.x + threadIdx.x;
    if (e < n_edges) {
        int pos = atomicAdd(&cursor[dst[e]], 1);
        csr_src[pos] = src[e];
    }
}

// ---- k4: fused gather-mean + [h,h_N]@W + b ---------------------------------
// One wave (64 lanes) per node; lane j = feature column j. Degree loop is
// wave-uniform (no divergence). W staged once per block, amortized over a
// grid-stride node loop.
__global__ __launch_bounds__(256) void sage_fused(
    const float* __restrict__ h,
    const int* __restrict__ row_start,
    const int* __restrict__ csr_src,
    const float* __restrict__ W,     // [128,64] row-major
    const float* __restrict__ b,
    float* __restrict__ out,
    int n_nodes)
{
    __shared__ float Wsh[128][64];   // 32 KB
    __shared__ float bsh[64];
    __shared__ float hsh[4][64];
    __shared__ float hnsh[4][64];

    int t = threadIdx.x;
    {   // stage W: 2048 float4s, 8 per thread
        float4* wd = (float4*)&Wsh[0][0];
        const float4* wsv = (const float4*)W;
        #pragma unroll
        for (int i = 0; i < 8; ++i) wd[t + i * 256] = wsv[t + i * 256];
    }
    if (t < 64) bsh[t] = b[t];
    __syncthreads();

    const int ln = t >> 6;           // wave id in block = local node
    const int j  = t & 63;           // feature column

    int ngroups = (n_nodes + 3) >> 2;
    for (int g = blockIdx.x; g < ngroups; g += gridDim.x) {
        int n = g * 4 + ln;
        float hv = 0.f, hn = 0.f;
        if (n < n_nodes) {
            hv = h[(size_t)n * IN_FEAT + j];
            int beg = row_start[n], end = row_start[n + 1];
            int e = beg;
            // 4-deep edge unroll for memory-level parallelism
            for (; e + 3 < end; e += 4) {
                int s0 = csr_src[e], s1 = csr_src[e + 1];
                int s2 = csr_src[e + 2], s3 = csr_src[e + 3];
                hn += h[(size_t)s0 * IN_FEAT + j];
                hn += h[(size_t)s1 * IN_FEAT + j];
                hn += h[(size_t)s2 * IN_FEAT + j];
                hn += h[(size_t)s3 * IN_FEAT + j];
            }
            for (; e < end; ++e) hn += h[(size_t)csr_src[e] * IN_FEAT + j];
            int deg = end - beg;
            hn *= (deg > 0) ? (1.0f / (float)deg) : 0.f;
        }
        hsh[ln][j]  = hv;
        hnsh[ln][j] = hn;
        __syncthreads();
        if (n < n_nodes) {
            float acc = bsh[j];
            #pragma unroll
            for (int k = 0; k < 64; ++k) {
                acc = fmaf(hsh[ln][k],  Wsh[k][j],      acc);
                acc = fmaf(hnsh[ln][k], Wsh[64 + k][j], acc);
            }
            out[(size_t)n * IN_FEAT + j] = acc;
        }
        __syncthreads();
    }
}

extern "C" void kernel_launch(void* const* d_in, const int* in_sizes, int n_in,
                              void* d_out, int out_size, void* d_ws, size_t ws_size,
                              hipStream_t stream) {
    const float* h   = (const float*)d_in[0];
    const int*   src = (const int*)d_in[1];
    const int*   dst = (const int*)d_in[2];
    const float* W   = (const float*)d_in[3];
    const float* b   = (const float*)d_in[4];
    float* out = (float*)d_out;

    const int n_nodes = in_sizes[0] / IN_FEAT;
    const int n_edges = in_sizes[1];

    // workspace layout (ints): cnt[N] | row_start[N+1] | cursor[N] | csr_src[E]
    int* cnt       = (int*)d_ws;
    int* row_start = cnt + n_nodes;
    int* cursor    = row_start + (n_nodes + 1);
    int* csr_src   = cursor + n_nodes;

    hipMemsetAsync(cnt, 0, (size_t)n_nodes * sizeof(int), stream);

    {
        int grid = (n_edges + 255) / 256;
        sage_hist<<<grid, 256, 0, stream>>>(dst, cnt, n_edges);
    }
    sage_scan<<<1, 1024, 0, stream>>>(cnt, row_start, cursor, n_nodes);
    {
        int grid = (n_edges + 255) / 256;
        sage_fill<<<grid, 256, 0, stream>>>(src, dst, cursor, csr_src, n_edges);
    }
    {
        int ngroups = (n_nodes + 3) / 4;
        int grid = ngroups < 2048 ? ngroups : 2048;
        sage_fused<<<grid, 256, 0, stream>>>(h, row_start, csr_src, W, b, out, n_nodes);
    }
}

// Round 3
// 230.460 us; speedup vs baseline: 3.6341x; 1.3702x over previous
//
#include <hip/hip_runtime.h>

// SAGEConv: h[50000,64] f32, src/dst[800000] int32, W[128,64] f32, b[64] f32
// out = concat(h, mean_{in-edges}(h[src])) @ W + b
//
// R3: parallel 3-phase scan (R2's single-block scan was 89us @ 0.17% occupancy)
//     + float4 gather with 4 edges/wave-iteration in the fused kernel.

#define IN_FEAT 64

// ---- k1: degree histogram --------------------------------------------------
__global__ __launch_bounds__(256) void sage_hist(
    const int* __restrict__ dst, int* __restrict__ cnt, int n_edges)
{
    int e = blockIdx.x * blockDim.x + threadIdx.x;
    if (e < n_edges) atomicAdd(&cnt[dst[e]], 1);
}

// ---- k2a: per-block scan (1024-element chunks) -----------------------------
__global__ __launch_bounds__(1024) void sage_scan_block(
    const int* __restrict__ cnt, int* __restrict__ row_start,
    int* __restrict__ blocksum, int n)
{
    __shared__ int sh[1024];
    int i = blockIdx.x * 1024 + (int)threadIdx.x;
    int v = (i < n) ? cnt[i] : 0;
    sh[threadIdx.x] = v;
    __syncthreads();
    #pragma unroll
    for (int off = 1; off < 1024; off <<= 1) {
        int t = (threadIdx.x >= (unsigned)off) ? sh[threadIdx.x - off] : 0;
        __syncthreads();
        sh[threadIdx.x] += t;
        __syncthreads();
    }
    if (i < n) row_start[i] = sh[threadIdx.x] - v;   // block-local exclusive
    if (threadIdx.x == 1023) blocksum[blockIdx.x] = sh[1023];
}

// ---- k2b: scan the block sums (one wave; nblocks <= 64) --------------------
__global__ __launch_bounds__(64) void sage_scan_sums(
    const int* __restrict__ blocksum, int* __restrict__ blockoff,
    int* __restrict__ total_out, int nblocks)
{
    int lane = threadIdx.x;
    int v = (lane < nblocks) ? blocksum[lane] : 0;
    int incl = v;
    #pragma unroll
    for (int off = 1; off < 64; off <<= 1) {
        int t = __shfl_up(incl, off);
        if (lane >= off) incl += t;
    }
    if (lane < nblocks) blockoff[lane] = incl - v;
    if (lane == 63) *total_out = incl;   // row_start[n_nodes]
}

// ---- k2c: add block offsets, write cursor ---------------------------------
__global__ __launch_bounds__(256) void sage_scan_add(
    int* __restrict__ row_start, int* __restrict__ cursor,
    const int* __restrict__ blockoff, int n)
{
    int i = blockIdx.x * 256 + (int)threadIdx.x;
    if (i < n) {
        int r = row_start[i] + blockoff[i >> 10];
        row_start[i] = r;
        cursor[i]    = r;
    }
}

// ---- k3: bucket edges by dst ----------------------------------------------
__global__ __launch_bounds__(256) void sage_fill(
    const int* __restrict__ src, const int* __restrict__ dst,
    int* __restrict__ cursor, int* __restrict__ csr_src, int n_edges)
{
    int e = blockIdx.x * blockDim.x + threadIdx.x;
    if (e < n_edges) {
        int pos = atomicAdd(&cursor[dst[e]], 1);
        csr_src[pos] = src[e];
    }
}

// ---- k4: fused gather-mean + [h,h_N]@W + b ---------------------------------
// One wave per node. Gather phase: 16 lanes/edge x float4 -> 4 edges per
// iteration, 2x unrolled (8 edges in flight), then __shfl_xor butterfly
// (masks 16,32) reduces the 4 edge-subgroups. MLP phase: lane j = column j.
__global__ __launch_bounds__(256) void sage_fused(
    const float* __restrict__ h,
    const int* __restrict__ row_start,
    const int* __restrict__ csr_src,
    const float* __restrict__ W,     // [128,64] row-major
    const float* __restrict__ b,
    float* __restrict__ out,
    int n_nodes)
{
    __shared__ float Wsh[128][64];   // 32 KB
    __shared__ float bsh[64];
    __shared__ float hsh[4][64];
    __shared__ float hnsh[4][64];

    int t = threadIdx.x;
    {   // stage W: 2048 float4s, 8 per thread
        float4* wd = (float4*)&Wsh[0][0];
        const float4* wsv = (const float4*)W;
        #pragma unroll
        for (int i = 0; i < 8; ++i) wd[t + i * 256] = wsv[t + i * 256];
    }
    if (t < 64) bsh[t] = b[t];
    __syncthreads();

    const int ln   = t >> 6;         // wave id in block = local node slot
    const int lane = t & 63;
    const int sub  = lane >> 4;      // edge subgroup 0..3
    const int q    = lane & 15;      // float4 column group 0..15

    int ngroups = (n_nodes + 3) >> 2;
    for (int g = blockIdx.x; g < ngroups; g += gridDim.x) {
        int n = g * 4 + ln;
        if (n < n_nodes) {
            // self feature (lane j = column j)
            hsh[ln][lane] = h[(size_t)n * IN_FEAT + lane];

            int beg = row_start[n], end = row_start[n + 1];
            float4 acc = make_float4(0.f, 0.f, 0.f, 0.f);
            int e = beg + sub;
            for (; e + 4 < end; e += 8) {
                int s0 = csr_src[e];
                int s1 = csr_src[e + 4];
                const float4 v0 = *(const float4*)(h + (size_t)s0 * IN_FEAT + q * 4);
                const float4 v1 = *(const float4*)(h + (size_t)s1 * IN_FEAT + q * 4);
                acc.x += v0.x + v1.x; acc.y += v0.y + v1.y;
                acc.z += v0.z + v1.z; acc.w += v0.w + v1.w;
            }
            if (e < end) {
                int s0 = csr_src[e];
                const float4 v0 = *(const float4*)(h + (size_t)s0 * IN_FEAT + q * 4);
                acc.x += v0.x; acc.y += v0.y; acc.z += v0.z; acc.w += v0.w;
            }
            // reduce across the 4 edge-subgroups: lanes {q, q+16, q+32, q+48}
            #pragma unroll
            for (int m = 16; m < 64; m <<= 1) {
                acc.x += __shfl_xor(acc.x, m);
                acc.y += __shfl_xor(acc.y, m);
                acc.z += __shfl_xor(acc.z, m);
                acc.w += __shfl_xor(acc.w, m);
            }
            int deg = end - beg;
            float inv = (deg > 0) ? (1.0f / (float)deg) : 0.f;
            if (sub == 0) {
                float4 r = make_float4(acc.x * inv, acc.y * inv, acc.z * inv, acc.w * inv);
                ((float4*)hnsh[ln])[q] = r;
            }
        }
        __syncthreads();
        if (n < n_nodes) {
            float accp = bsh[lane];
            #pragma unroll
            for (int k = 0; k < 64; ++k) {
                accp = fmaf(hsh[ln][k],  Wsh[k][lane],      accp);
                accp = fmaf(hnsh[ln][k], Wsh[64 + k][lane], accp);
            }
            out[(size_t)n * IN_FEAT + lane] = accp;
        }
        __syncthreads();
    }
}

extern "C" void kernel_launch(void* const* d_in, const int* in_sizes, int n_in,
                              void* d_out, int out_size, void* d_ws, size_t ws_size,
                              hipStream_t stream) {
    const float* h   = (const float*)d_in[0];
    const int*   src = (const int*)d_in[1];
    const int*   dst = (const int*)d_in[2];
    const float* W   = (const float*)d_in[3];
    const float* b   = (const float*)d_in[4];
    float* out = (float*)d_out;

    const int n_nodes = in_sizes[0] / IN_FEAT;
    const int n_edges = in_sizes[1];

    // ws layout (ints): cnt[N] | row_start[N+1] | cursor[N] | csr_src[E] |
    //                   blocksum[64] | blockoff[64]
    int* cnt       = (int*)d_ws;
    int* row_start = cnt + n_nodes;
    int* cursor    = row_start + (n_nodes + 1);
    int* csr_src   = cursor + n_nodes;
    int* blocksum  = csr_src + n_edges;
    int* blockoff  = blocksum + 64;

    const int nscan = (n_nodes + 1023) / 1024;   // 49 for N=50000

    hipMemsetAsync(cnt, 0, (size_t)n_nodes * sizeof(int), stream);

    sage_hist<<<(n_edges + 255) / 256, 256, 0, stream>>>(dst, cnt, n_edges);
    sage_scan_block<<<nscan, 1024, 0, stream>>>(cnt, row_start, blocksum, n_nodes);
    sage_scan_sums<<<1, 64, 0, stream>>>(blocksum, blockoff, &row_start[n_nodes], nscan);
    sage_scan_add<<<(n_nodes + 255) / 256, 256, 0, stream>>>(row_start, cursor, blockoff, n_nodes);
    sage_fill<<<(n_edges + 255) / 256, 256, 0, stream>>>(src, dst, cursor, csr_src, n_edges);

    {
        int ngroups = (n_nodes + 3) / 4;
        int grid = ngroups < 2048 ? ngroups : 2048;
        sage_fused<<<grid, 256, 0, stream>>>(h, row_start, csr_src, W, b, out, n_nodes);
    }
}

// Round 4
// 217.765 us; speedup vs baseline: 3.8460x; 1.0583x over previous
//
#include <hip/hip_runtime.h>

// SAGEConv: h[50000,64] f32, src/dst[800000] int32, W[128,64] f32, b[64] f32
// out = concat(h, mean_{in-edges}(h[src])) @ W + b
//
// R4: 5-dispatch pipeline (memset, hist, scan_block, fill, fused).
//  - scan_sums/scan_add removed: fill+fused re-scan the 49 block sums per block.
//  - fused: block=1024 (16 waves, one 32KB W stage), 64 nodes/block-group,
//    wave-private LDS (no in-loop barriers), MLP 4 nodes/wave with float4
//    acc + ds_read_b128 W rows (4x less W LDS traffic), self-row read from
//    global (broadcast, L1/L2-hit) to stay under the 64KB static LDS limit.

#define IN_FEAT 64

// ---- k1: degree histogram --------------------------------------------------
__global__ __launch_bounds__(256) void sage_hist(
    const int* __restrict__ dst, int* __restrict__ cnt, int n_edges)
{
    int e = blockIdx.x * 256 + (int)threadIdx.x;
    if (e < n_edges) atomicAdd(&cnt[dst[e]], 1);
}

// ---- k2: block-local exclusive scan over n_nodes+1 elements ----------------
// row_start[i] = exclusive prefix WITHIN its 1024-chunk; blocksum[b] = chunk sum.
__global__ __launch_bounds__(1024) void sage_scan_block(
    const int* __restrict__ cnt, int* __restrict__ row_start,
    int* __restrict__ cursor, int* __restrict__ blocksum, int n_nodes)
{
    __shared__ int sh[1024];
    int i = blockIdx.x * 1024 + (int)threadIdx.x;
    int v = (i < n_nodes) ? cnt[i] : 0;
    sh[threadIdx.x] = v;
    __syncthreads();
    #pragma unroll
    for (int off = 1; off < 1024; off <<= 1) {
        int t = (threadIdx.x >= (unsigned)off) ? sh[threadIdx.x - off] : 0;
        __syncthreads();
        sh[threadIdx.x] += t;
        __syncthreads();
    }
    int ex = sh[threadIdx.x] - v;
    if (i <= n_nodes) {
        row_start[i] = ex;
        if (i < n_nodes) cursor[i] = ex;
    }
    if (threadIdx.x == 1023) blocksum[blockIdx.x] = sh[1023];
}

// ---- k3: bucket edges by dst (adds per-chunk offset from a tiny LDS scan) --
__global__ __launch_bounds__(256) void sage_fill(
    const int* __restrict__ src, const int* __restrict__ dst,
    int* __restrict__ cursor, const int* __restrict__ blocksum,
    int* __restrict__ csr_src, int n_edges, int nscan)
{
    __shared__ int boffsh[64];
    if (threadIdx.x < 64) {
        int lane = threadIdx.x;
        int v = (lane < nscan) ? blocksum[lane] : 0;
        int incl = v;
        #pragma unroll
        for (int off = 1; off < 64; off <<= 1) {
            int t = __shfl_up(incl, off);
            if (lane >= off) incl += t;
        }
        boffsh[lane] = incl - v;
    }
    __syncthreads();
    int e = blockIdx.x * 256 + (int)threadIdx.x;
    if (e < n_edges) {
        int d = dst[e];
        int pos = atomicAdd(&cursor[d], 1) + boffsh[d >> 10];
        csr_src[pos] = src[e];
    }
}

// ---- k4: fused gather-mean + [h,h_N]@W + b ---------------------------------
// Block = 1024 threads (16 waves), group = 64 nodes. Wave w owns nodes
// 4w..4w+3 for BOTH phases -> all in-loop LDS traffic is wave-private, no
// barriers in the loop.
//   Gather (per node, sequential x4): 16 lanes/edge x float4, 2x unroll,
//   __shfl_xor(16,32) butterfly, mean written to hn[slot] (row pad 68 floats:
//   16B-aligned float4 + bank-spread across the wave's 4 slots).
//   MLP: lane = (nl, q) -> node 4w+nl, columns 4q..4q+3. Self row from global
//   (16-lane broadcast float4, L1/L2-hit), hn from LDS, W rows ds_read_b128
//   shared by 4 nodes.
__global__ __launch_bounds__(1024, 8) void sage_fused(
    const float* __restrict__ h,
    const int* __restrict__ row_start,
    const int* __restrict__ blocksum,
    const int* __restrict__ csr_src,
    const float* __restrict__ W,     // [128,64] row-major
    const float* __restrict__ b,
    float* __restrict__ out,
    int n_nodes, int nscan)
{
    __shared__ float Wsh[128][64];   // 32 KB
    __shared__ float bsh[64];
    __shared__ float hn[64][68];     // 17.4 KB, pad 68 (16B-aligned, bank-spread)
    __shared__ int boffsh[64];
    // total static LDS ~50.7 KB -> 2 blocks/CU (32 waves = 100% occupancy)

    const int t = (int)threadIdx.x;
    {   // stage W: 2048 float4s, 2 per thread
        float4* wd = (float4*)&Wsh[0][0];
        const float4* wsv = (const float4*)W;
        wd[t]        = wsv[t];
        wd[t + 1024] = wsv[t + 1024];
    }
    if (t < 64) bsh[t] = b[t];
    if (t >= 64 && t < 128) {        // wave 1: scan the chunk sums
        int lane = t - 64;
        int v = (lane < nscan) ? blocksum[lane] : 0;
        int incl = v;
        #pragma unroll
        for (int off = 1; off < 64; off <<= 1) {
            int x = __shfl_up(incl, off);
            if (lane >= off) incl += x;
        }
        boffsh[lane] = incl - v;
    }
    __syncthreads();

    const int w    = t >> 6;         // wave 0..15
    const int lane = t & 63;
    const int sub  = lane >> 4;      // gather: edge subgroup | MLP: node-in-quad
    const int q    = lane & 15;      // float4 column group

    const int ngroups = (n_nodes + 63) >> 6;
    for (int g = blockIdx.x; g < ngroups; g += gridDim.x) {
        const int nbase = g * 64 + w * 4;

        // ---- gather phase: 4 nodes sequentially (wave-uniform trip counts) --
        #pragma unroll
        for (int i = 0; i < 4; ++i) {
            int n = nbase + i;
            if (n >= n_nodes) break;             // wave-uniform
            int slot = w * 4 + i;
            int beg = row_start[n]     + boffsh[n >> 10];
            int end = row_start[n + 1] + boffsh[(n + 1) >> 10];
            float4 acc = make_float4(0.f, 0.f, 0.f, 0.f);
            int e = beg + sub;
            for (; e + 4 < end; e += 8) {
                int s0 = csr_src[e], s1 = csr_src[e + 4];
                const float4 v0 = *(const float4*)(h + (size_t)s0 * IN_FEAT + q * 4);
                const float4 v1 = *(const float4*)(h + (size_t)s1 * IN_FEAT + q * 4);
                acc.x += v0.x + v1.x; acc.y += v0.y + v1.y;
                acc.z += v0.z + v1.z; acc.w += v0.w + v1.w;
            }
            if (e < end) {
                int s0 = csr_src[e];
                const float4 v0 = *(const float4*)(h + (size_t)s0 * IN_FEAT + q * 4);
                acc.x += v0.x; acc.y += v0.y; acc.z += v0.z; acc.w += v0.w;
            }
            #pragma unroll
            for (int m = 16; m < 64; m <<= 1) {
                acc.x += __shfl_xor(acc.x, m);
                acc.y += __shfl_xor(acc.y, m);
                acc.z += __shfl_xor(acc.z, m);
                acc.w += __shfl_xor(acc.w, m);
            }
            int deg = end - beg;
            float inv = (deg > 0) ? (1.0f / (float)deg) : 0.f;
            if (sub == 0)
                *(float4*)&hn[slot][q * 4] =
                    make_float4(acc.x * inv, acc.y * inv, acc.z * inv, acc.w * inv);
        }
        __builtin_amdgcn_wave_barrier();  // wave-private LDS: scheduling fence only

        // ---- MLP phase: lane (sub,q) -> node nbase+sub, columns 4q..4q+3 ----
        {
            int n2 = nbase + sub;
            if (n2 < n_nodes) {
                int slot = w * 4 + sub;
                const float* hrow = h + (size_t)n2 * IN_FEAT;
                float4 acc = ((const float4*)bsh)[q];
                #pragma unroll
                for (int k4 = 0; k4 < 16; ++k4) {
                    const float4 hq = *(const float4*)(hrow + k4 * 4);  // bcast x16
                    #pragma unroll
                    for (int c = 0; c < 4; ++c) {
                        float hv = (&hq.x)[c];
                        const float4 wv = *(const float4*)&Wsh[k4 * 4 + c][q * 4];
                        acc.x = fmaf(hv, wv.x, acc.x);
                        acc.y = fmaf(hv, wv.y, acc.y);
                        acc.z = fmaf(hv, wv.z, acc.z);
                        acc.w = fmaf(hv, wv.w, acc.w);
                    }
                }
                #pragma unroll 16
                for (int k = 0; k < 64; ++k) {
                    float hv = hn[slot][k];
                    const float4 wv = *(const float4*)&Wsh[64 + k][q * 4];
                    acc.x = fmaf(hv, wv.x, acc.x);
                    acc.y = fmaf(hv, wv.y, acc.y);
                    acc.z = fmaf(hv, wv.z, acc.z);
                    acc.w = fmaf(hv, wv.w, acc.w);
                }
                *(float4*)(out + (size_t)n2 * IN_FEAT + q * 4) = acc;
            }
        }
        __builtin_amdgcn_wave_barrier();
    }
}

extern "C" void kernel_launch(void* const* d_in, const int* in_sizes, int n_in,
                              void* d_out, int out_size, void* d_ws, size_t ws_size,
                              hipStream_t stream) {
    const float* h   = (const float*)d_in[0];
    const int*   src = (const int*)d_in[1];
    const int*   dst = (const int*)d_in[2];
    const float* W   = (const float*)d_in[3];
    const float* b   = (const float*)d_in[4];
    float* out = (float*)d_out;

    const int n_nodes = in_sizes[0] / IN_FEAT;
    const int n_edges = in_sizes[1];

    // ws layout (ints): cnt[N] | row_start[N+1] | cursor[N] | csr_src[E] | blocksum[64]
    int* cnt       = (int*)d_ws;
    int* row_start = cnt + n_nodes;
    int* cursor    = row_start + (n_nodes + 1);
    int* csr_src   = cursor + n_nodes;
    int* blocksum  = csr_src + n_edges;

    const int nscan = (n_nodes + 1 + 1023) / 1024;   // 49 chunks for N=50000

    hipMemsetAsync(cnt, 0, (size_t)n_nodes * sizeof(int), stream);

    sage_hist<<<(n_edges + 255) / 256, 256, 0, stream>>>(dst, cnt, n_edges);
    sage_scan_block<<<nscan, 1024, 0, stream>>>(cnt, row_start, cursor, blocksum, n_nodes);
    sage_fill<<<(n_edges + 255) / 256, 256, 0, stream>>>(src, dst, cursor, blocksum,
                                                         csr_src, n_edges, nscan);
    {
        int ngroups = (n_nodes + 63) / 64;           // 782
        int grid = ngroups < 512 ? ngroups : 512;    // 2 blocks/CU
        sage_fused<<<grid, 1024, 0, stream>>>(h, row_start, blocksum, csr_src,
                                              W, b, out, n_nodes, nscan);
    }
}

// Round 5
// 153.324 us; speedup vs baseline: 5.4624x; 1.4203x over previous
//
#include <hip/hip_runtime.h>

// SAGEConv: h[50000,64] f32, src/dst[800000] int32, W[128,64] f32, b[64] f32
// out = concat(h, mean_{in-edges}(h[src])) @ W + b
//
// R5: CSR build via two-level bucket sort (kills R4's sage_fill: 65us,
// WRITE_SIZE 53MB from 800k scattered 4B writes + 800k global atomic-returns).
//  k1 histk : bucket counts (dst>>7), LDS-aggregated -> ~100k global atomics
//  k2 scank : scan 391 bucket counts (1 block)
//  k3 bucket: tile->LDS hist, per-bucket space reservation, coalesced int2
//             pair writes (~64B runs per bucket per tile)
//  k4 csr   : 1 block/bucket, per-node cursors in LDS, scatter confined to
//             the bucket's ~8KB csr window (single-block L2-local), writes
//             absolute row_start
//  k5 fused : unchanged from R4 except row_start is absolute now.
// NOTE: assumes n_nodes <= 65536 (bucket count K = ceil(N/128) <= 512).

#define IN_FEAT 64
#define KB_SHIFT 7            // 128 nodes per bucket
#define KMAX 512

// ---- k1: bucket histogram with LDS pre-aggregation -------------------------
__global__ __launch_bounds__(256) void sage_histk(
    const int* __restrict__ dst, int* __restrict__ histc, int n_edges)
{
    __shared__ int cnt[KMAX];
    int t = (int)threadIdx.x;
    cnt[t] = 0; cnt[t + 256] = 0;
    __syncthreads();
    int base = blockIdx.x * 4096;
    #pragma unroll
    for (int i = 0; i < 16; ++i) {
        int e = base + t + i * 256;
        if (e < n_edges) atomicAdd(&cnt[dst[e] >> KB_SHIFT], 1);
    }
    __syncthreads();
    #pragma unroll
    for (int k = t; k < KMAX; k += 256)
        if (cnt[k]) atomicAdd(&histc[k], cnt[k]);
}

// ---- k2: scan bucket counts (single block, K <= 512) -----------------------
__global__ __launch_bounds__(512) void sage_scank(
    const int* __restrict__ histc, int* __restrict__ pbase,
    int* __restrict__ cursorA, int K)
{
    __shared__ int sh[512];
    int t = (int)threadIdx.x;
    int v = (t < K) ? histc[t] : 0;
    sh[t] = v;
    __syncthreads();
    #pragma unroll
    for (int off = 1; off < 512; off <<= 1) {
        int x = (t >= off) ? sh[t - off] : 0;
        __syncthreads();
        sh[t] += x;
        __syncthreads();
    }
    int ex = sh[t] - v;
    if (t < K) { pbase[t] = ex; cursorA[t] = ex; }
    if (t == 511) pbase[K] = sh[511];   // == n_edges
}

// ---- k3: bucket the edges (coalesced pair writes) --------------------------
__global__ __launch_bounds__(256) void sage_bucket(
    const int* __restrict__ src, const int* __restrict__ dst,
    int* __restrict__ cursorA, int2* __restrict__ pairs, int n_edges)
{
    __shared__ int cnt[KMAX];
    __shared__ int base[KMAX];
    __shared__ int rnk[KMAX];
    int t = (int)threadIdx.x;
    #pragma unroll
    for (int k = t; k < KMAX; k += 256) { cnt[k] = 0; rnk[k] = 0; }
    __syncthreads();

    int tb = blockIdx.x * 4096;
    int d[16], s[16], kb[16];
    #pragma unroll
    for (int i = 0; i < 16; ++i) {
        int e = tb + t + i * 256;
        kb[i] = -1;
        if (e < n_edges) {
            d[i] = dst[e]; s[i] = src[e];
            kb[i] = d[i] >> KB_SHIFT;
            atomicAdd(&cnt[kb[i]], 1);
        }
    }
    __syncthreads();
    #pragma unroll
    for (int k = t; k < KMAX; k += 256) {
        int c = cnt[k];
        base[k] = c ? atomicAdd(&cursorA[k], c) : 0;
    }
    __syncthreads();
    #pragma unroll
    for (int i = 0; i < 16; ++i) {
        if (kb[i] >= 0) {
            int r = atomicAdd(&rnk[kb[i]], 1);
            pairs[base[kb[i]] + r] = make_int2(d[i], s[i]);
        }
    }
}

// ---- k4: per-bucket fine CSR (LDS cursors, L2-local scatter) ---------------
__global__ __launch_bounds__(256) void sage_csr(
    const int2* __restrict__ pairs, const int* __restrict__ pbase,
    int* __restrict__ row_start, int* __restrict__ csr_src,
    int n_nodes, int K)
{
    __shared__ int cnt[128];
    __shared__ int sh[128];
    __shared__ int cur[128];
    int b = blockIdx.x;
    int t = (int)threadIdx.x;
    int nlo = b << KB_SHIFT;
    int nn  = min(128, n_nodes - nlo);      // nodes in this bucket
    int pb = pbase[b], pe = pbase[b + 1];

    if (t < 128) cnt[t] = 0;
    __syncthreads();
    for (int e = pb + t; e < pe; e += 256)
        atomicAdd(&cnt[pairs[e].x - nlo], 1);
    __syncthreads();
    // exclusive scan over 128 counters
    int v = (t < 128) ? cnt[t] : 0;
    if (t < 128) sh[t] = v;
    __syncthreads();
    #pragma unroll
    for (int off = 1; off < 128; off <<= 1) {
        int x = (t < 128 && t >= off) ? sh[t - off] : 0;
        __syncthreads();
        if (t < 128) sh[t] += x;
        __syncthreads();
    }
    if (t < nn) {
        int abs0 = pb + sh[t] - v;          // absolute exclusive offset
        row_start[nlo + t] = abs0;
        cur[t] = abs0;
    }
    if (b == K - 1 && t == 0) row_start[n_nodes] = pe;
    __syncthreads();
    for (int e = pb + t; e < pe; e += 256) {
        int2 p = pairs[e];
        int pos = atomicAdd(&cur[p.x - nlo], 1);
        csr_src[pos] = p.y;
    }
}

// ---- k5: fused gather-mean + [h,h_N]@W + b ---------------------------------
// Block = 1024 threads (16 waves). Wave w owns nodes 4w..4w+3 for both
// phases -> wave-private LDS, no in-loop barriers. Gather: 16 lanes/edge x
// float4, 2x unroll, __shfl_xor(16,32) reduce. MLP: lane (sub,q) -> node
// nbase+sub, columns 4q..4q+3; W rows via ds_read_b128 shared by 4 nodes.
__global__ __launch_bounds__(1024, 8) void sage_fused(
    const float* __restrict__ h,
    const int* __restrict__ row_start,
    const int* __restrict__ csr_src,
    const float* __restrict__ W,     // [128,64] row-major
    const float* __restrict__ b,
    float* __restrict__ out,
    int n_nodes)
{
    __shared__ float Wsh[128][64];   // 32 KB
    __shared__ float bsh[64];
    __shared__ float hn[64][68];     // pad 68: 16B-aligned + bank-spread

    const int t = (int)threadIdx.x;
    {   // stage W: 2048 float4s, 2 per thread
        float4* wd = (float4*)&Wsh[0][0];
        const float4* wsv = (const float4*)W;
        wd[t]        = wsv[t];
        wd[t + 1024] = wsv[t + 1024];
    }
    if (t < 64) bsh[t] = b[t];
    __syncthreads();

    const int w    = t >> 6;
    const int lane = t & 63;
    const int sub  = lane >> 4;
    const int q    = lane & 15;

    const int ngroups = (n_nodes + 63) >> 6;
    for (int g = blockIdx.x; g < ngroups; g += gridDim.x) {
        const int nbase = g * 64 + w * 4;

        #pragma unroll
        for (int i = 0; i < 4; ++i) {
            int n = nbase + i;
            if (n >= n_nodes) break;             // wave-uniform
            int slot = w * 4 + i;
            int beg = row_start[n], end = row_start[n + 1];
            float4 acc = make_float4(0.f, 0.f, 0.f, 0.f);
            int e = beg + sub;
            for (; e + 4 < end; e += 8) {
                int s0 = csr_src[e], s1 = csr_src[e + 4];
                const float4 v0 = *(const float4*)(h + (size_t)s0 * IN_FEAT + q * 4);
                const float4 v1 = *(const float4*)(h + (size_t)s1 * IN_FEAT + q * 4);
                acc.x += v0.x + v1.x; acc.y += v0.y + v1.y;
                acc.z += v0.z + v1.z; acc.w += v0.w + v1.w;
            }
            if (e < end) {
                int s0 = csr_src[e];
                const float4 v0 = *(const float4*)(h + (size_t)s0 * IN_FEAT + q * 4);
                acc.x += v0.x; acc.y += v0.y; acc.z += v0.z; acc.w += v0.w;
            }
            #pragma unroll
            for (int m = 16; m < 64; m <<= 1) {
                acc.x += __shfl_xor(acc.x, m);
                acc.y += __shfl_xor(acc.y, m);
                acc.z += __shfl_xor(acc.z, m);
                acc.w += __shfl_xor(acc.w, m);
            }
            int deg = end - beg;
            float inv = (deg > 0) ? (1.0f / (float)deg) : 0.f;
            if (sub == 0)
                *(float4*)&hn[slot][q * 4] =
                    make_float4(acc.x * inv, acc.y * inv, acc.z * inv, acc.w * inv);
        }
        __builtin_amdgcn_wave_barrier();

        {
            int n2 = nbase + sub;
            if (n2 < n_nodes) {
                int slot = w * 4 + sub;
                const float* hrow = h + (size_t)n2 * IN_FEAT;
                float4 acc = ((const float4*)bsh)[q];
                #pragma unroll
                for (int k4 = 0; k4 < 16; ++k4) {
                    const float4 hq = *(const float4*)(hrow + k4 * 4);
                    #pragma unroll
                    for (int c = 0; c < 4; ++c) {
                        float hv = (&hq.x)[c];
                        const float4 wv = *(const float4*)&Wsh[k4 * 4 + c][q * 4];
                        acc.x = fmaf(hv, wv.x, acc.x);
                        acc.y = fmaf(hv, wv.y, acc.y);
                        acc.z = fmaf(hv, wv.z, acc.z);
                        acc.w = fmaf(hv, wv.w, acc.w);
                    }
                }
                #pragma unroll 16
                for (int k = 0; k < 64; ++k) {
                    float hv = hn[slot][k];
                    const float4 wv = *(const float4*)&Wsh[64 + k][q * 4];
                    acc.x = fmaf(hv, wv.x, acc.x);
                    acc.y = fmaf(hv, wv.y, acc.y);
                    acc.z = fmaf(hv, wv.z, acc.z);
                    acc.w = fmaf(hv, wv.w, acc.w);
                }
                *(float4*)(out + (size_t)n2 * IN_FEAT + q * 4) = acc;
            }
        }
        __builtin_amdgcn_wave_barrier();
    }
}

extern "C" void kernel_launch(void* const* d_in, const int* in_sizes, int n_in,
                              void* d_out, int out_size, void* d_ws, size_t ws_size,
                              hipStream_t stream) {
    const float* h   = (const float*)d_in[0];
    const int*   src = (const int*)d_in[1];
    const int*   dst = (const int*)d_in[2];
    const float* W   = (const float*)d_in[3];
    const float* b   = (const float*)d_in[4];
    float* out = (float*)d_out;

    const int n_nodes = in_sizes[0] / IN_FEAT;
    const int n_edges = in_sizes[1];
    const int K = (n_nodes + 127) >> KB_SHIFT;     // 391 for N=50000

    // ws layout (ints): pairs[2E] | csr_src[E] | row_start[N+1] |
    //                   histc[K] | pbase[K+1] | cursorA[K]
    int2* pairs    = (int2*)d_ws;                  // 8B-aligned at base
    int* csr_src   = (int*)d_ws + 2 * (size_t)n_edges;
    int* row_start = csr_src + n_edges;
    int* histc     = row_start + (n_nodes + 1);
    int* pbase     = histc + K;
    int* cursorA   = pbase + (K + 1);

    hipMemsetAsync(histc, 0, (size_t)K * sizeof(int), stream);

    const int ntiles = (n_edges + 4095) / 4096;    // 196
    sage_histk<<<ntiles, 256, 0, stream>>>(dst, histc, n_edges);
    sage_scank<<<1, 512, 0, stream>>>(histc, pbase, cursorA, K);
    sage_bucket<<<ntiles, 256, 0, stream>>>(src, dst, cursorA, pairs, n_edges);
    sage_csr<<<K, 256, 0, stream>>>(pairs, pbase, row_start, csr_src, n_nodes, K);
    {
        int ngroups = (n_nodes + 63) / 64;         // 782
        int grid = ngroups < 512 ? ngroups : 512;  // 2 blocks/CU
        sage_fused<<<grid, 1024, 0, stream>>>(h, row_start, csr_src, W, b, out, n_nodes);
    }
}